// Round 1
// 1685.145 us; speedup vs baseline: 1.0517x; 1.0517x over previous
//
#include <hip/hip_runtime.h>
#include <cstdio>
#include <cstdint>
#include <cstddef>

// Problem constants
#define B_ 2
#define S_ 2048
#define D_ 2048
#define H_ 16
#define HD_ 128
#define FF_ 5632

typedef unsigned short u16;
typedef float f32x4 __attribute__((ext_vector_type(4)));
typedef __bf16 bf16x8 __attribute__((ext_vector_type(8)));
typedef short s16x8 __attribute__((ext_vector_type(8)));
typedef short s16x4 __attribute__((ext_vector_type(4)));

__device__ __forceinline__ u16 f2bf(float f) {
  unsigned u = __builtin_bit_cast(unsigned, f);
  u += 0x7fffu + ((u >> 16) & 1u);   // RNE
  return (u16)(u >> 16);
}
__device__ __forceinline__ float bf2f(u16 h) {
  unsigned u = ((unsigned)h) << 16;
  return __builtin_bit_cast(float, u);
}

// async global->LDS, 16B per lane. LDS dest must be wave-uniform base + lane*16.
__device__ __forceinline__ void async_ld16(const void* g, void* l) {
  __builtin_amdgcn_global_load_lds(
      (__attribute__((address_space(1))) void*)(unsigned long long)g,
      (__attribute__((address_space(3))) void*)(unsigned)(unsigned long long)l,
      16, 0, 0);
}

// ---------------- f32 -> bf16 convert (8 elems/thread) ----------------
__global__ __launch_bounds__(256) void k_cvt_bf16(
    const float* __restrict__ in, u16* __restrict__ out, int n8) {
  const int i = blockIdx.x * 256 + threadIdx.x;
  if (i >= n8) return;
  const float4* p = (const float4*)in + (size_t)i * 2;
  const float4 a = p[0], b = p[1];
  s16x8 o;
  o[0] = (short)f2bf(a.x); o[1] = (short)f2bf(a.y);
  o[2] = (short)f2bf(a.z); o[3] = (short)f2bf(a.w);
  o[4] = (short)f2bf(b.x); o[5] = (short)f2bf(b.y);
  o[6] = (short)f2bf(b.z); o[7] = (short)f2bf(b.w);
  *(s16x8*)(out + (size_t)i * 8) = o;
}

// ---------------- RMSNorm (f32 in, bf16 out), one block per row of 2048 ----------------
__global__ __launch_bounds__(256) void k_rmsnorm_bf16(
    const float* __restrict__ x, const float* __restrict__ w, u16* __restrict__ out) {
  const int row = blockIdx.x;
  const int t = threadIdx.x;
  const float* xr = x + (size_t)row * D_;
  const float4 a = ((const float4*)xr)[t];
  const float4 b = ((const float4*)xr)[t + 256];
  float ss = a.x * a.x + a.y * a.y + a.z * a.z + a.w * a.w +
             b.x * b.x + b.y * b.y + b.z * b.z + b.w * b.w;
#pragma unroll
  for (int off = 1; off < 64; off <<= 1) ss += __shfl_xor(ss, off);
  __shared__ float red[4];
  if ((t & 63) == 0) red[t >> 6] = ss;
  __syncthreads();
  const float scale =
      rsqrtf((red[0] + red[1] + red[2] + red[3]) * (1.0f / (float)D_) + 1e-5f);
  const float4 wa = ((const float4*)w)[t];
  const float4 wb = ((const float4*)w)[t + 256];
  u16* orow = out + (size_t)row * D_;
  s16x4 o0, o1;
  o0[0] = (short)f2bf(a.x * scale * wa.x);
  o0[1] = (short)f2bf(a.y * scale * wa.y);
  o0[2] = (short)f2bf(a.z * scale * wa.z);
  o0[3] = (short)f2bf(a.w * scale * wa.w);
  o1[0] = (short)f2bf(b.x * scale * wb.x);
  o1[1] = (short)f2bf(b.y * scale * wb.y);
  o1[2] = (short)f2bf(b.z * scale * wb.z);
  o1[3] = (short)f2bf(b.w * scale * wb.w);
  *(s16x4*)(orow + t * 4) = o0;
  *(s16x4*)(orow + (t + 256) * 4) = o1;
}

// ---------------- ff + residual -> RMSNorm -> f32 out ----------------
__global__ __launch_bounds__(256) void k_add_rmsnorm(
    const float* __restrict__ ff, const float* __restrict__ res,
    const float* __restrict__ w, float* __restrict__ out) {
  const int row = blockIdx.x;
  const int t = threadIdx.x;
  const float4 fa = ((const float4*)(ff + (size_t)row * D_))[t];
  const float4 fb = ((const float4*)(ff + (size_t)row * D_))[t + 256];
  const float4 ra = ((const float4*)(res + (size_t)row * D_))[t];
  const float4 rb = ((const float4*)(res + (size_t)row * D_))[t + 256];
  float4 ha, hb2;
  ha.x = fa.x + ra.x; ha.y = fa.y + ra.y; ha.z = fa.z + ra.z; ha.w = fa.w + ra.w;
  hb2.x = fb.x + rb.x; hb2.y = fb.y + rb.y; hb2.z = fb.z + rb.z; hb2.w = fb.w + rb.w;
  float ss = ha.x * ha.x + ha.y * ha.y + ha.z * ha.z + ha.w * ha.w +
             hb2.x * hb2.x + hb2.y * hb2.y + hb2.z * hb2.z + hb2.w * hb2.w;
#pragma unroll
  for (int off = 1; off < 64; off <<= 1) ss += __shfl_xor(ss, off);
  __shared__ float red[4];
  if ((t & 63) == 0) red[t >> 6] = ss;
  __syncthreads();
  const float scale =
      rsqrtf((red[0] + red[1] + red[2] + red[3]) * (1.0f / (float)D_) + 1e-5f);
  const float4 wa = ((const float4*)w)[t];
  const float4 wb = ((const float4*)w)[t + 256];
  float4 o0, o1;
  o0.x = ha.x * scale * wa.x; o0.y = ha.y * scale * wa.y;
  o0.z = ha.z * scale * wa.z; o0.w = ha.w * scale * wa.w;
  o1.x = hb2.x * scale * wb.x; o1.y = hb2.y * scale * wb.y;
  o1.z = hb2.z * scale * wb.z; o1.w = hb2.w * scale * wb.w;
  float* orow = out + (size_t)row * D_;
  ((float4*)orow)[t] = o0;
  ((float4*)orow)[t + 256] = o1;
}

// ---------------- silu(g)*u from merged gcat [4096, 11264] -> gbuf [4096, 5632] ----------------
__global__ __launch_bounds__(256) void k_silu_mul(
    const u16* __restrict__ gcat, u16* __restrict__ out) {
  const int idx = blockIdx.x * 256 + threadIdx.x;  // 4096*704 total
  const int row = idx / 704;
  const int c = (idx - row * 704) * 8;
  const s16x8 gv = *(const s16x8*)(gcat + (size_t)row * 11264 + c);
  const s16x8 uv = *(const s16x8*)(gcat + (size_t)row * 11264 + 5632 + c);
  s16x8 ov;
#pragma unroll
  for (int j = 0; j < 8; j++) {
    float gf = bf2f((u16)gv[j]);
    float uf = bf2f((u16)uv[j]);
    float s = gf / (1.0f + __expf(-gf));
    ov[j] = (short)f2bf(s * uf);
  }
  *(s16x8*)(out + (size_t)row * 5632 + c) = ov;
}

// ---------------- bf16 GEMM (m97 128x128 structure) for small-N shapes ----------------
// MODE 0: bf16 C (ldc). MODE 1: f32 C (ldc).
template <int MODE>
__global__ __launch_bounds__(256, 2) void k_gemm_bt(
    const u16* __restrict__ A, const u16* __restrict__ Bm, void* __restrict__ Cp,
    u16* __restrict__ VT, int M, int N, int K, int ldc) {
  __shared__ __align__(16) u16 sA[128 * 32];
  __shared__ __align__(16) u16 sB[128 * 32];
  const int tid = threadIdx.x;
  const int lane = tid & 63;
  const int wave = tid >> 6;
  const int l15 = lane & 15;
  const int quad = lane >> 4;
  const int wm = (wave >> 1) * 64;
  const int wn = (wave & 1) * 64;
  const int bm = blockIdx.y * 128;
  const int bn = blockIdx.x * 128;

  const int sr = tid >> 2;
  const int sc = (tid & 3) * 8;
  const u16* pa = A + (size_t)(bm + sr) * K + sc;
  const u16* pb = Bm + (size_t)(bn + sr) * K + sc;
  u16* la = &sA[tid * 8];
  u16* lb = &sB[tid * 8];
  const size_t half = (size_t)64 * K;

  f32x4 acc[4][4] = {};
  const u16* ra = &sA[(wm + l15) * 32 + quad * 8];
  const u16* rb = &sB[(wn + l15) * 32 + quad * 8];

  for (int k0 = 0; k0 < K; k0 += 32) {
    async_ld16(pa, la);
    async_ld16(pa + half, la + 2048);
    async_ld16(pb, lb);
    async_ld16(pb + half, lb + 2048);
    pa += 32;
    pb += 32;
    __syncthreads();
    bf16x8 af[4], bfr[4];
#pragma unroll
    for (int i = 0; i < 4; i++) af[i] = *(const bf16x8*)(ra + i * 512);
#pragma unroll
    for (int j = 0; j < 4; j++) bfr[j] = *(const bf16x8*)(rb + j * 512);
#pragma unroll
    for (int i = 0; i < 4; i++)
#pragma unroll
      for (int j = 0; j < 4; j++)
        acc[i][j] = __builtin_amdgcn_mfma_f32_16x16x32_bf16(af[i], bfr[j],
                                                            acc[i][j], 0, 0, 0);
    __syncthreads();
  }

#pragma unroll
  for (int i = 0; i < 4; i++)
#pragma unroll
    for (int j = 0; j < 4; j++) {
      const int row0 = bm + wm + i * 16 + quad * 4;
      const int col = bn + wn + j * 16 + l15;
      if (MODE == 1) {
        float* C = (float*)Cp;
#pragma unroll
        for (int r = 0; r < 4; r++)
          C[(size_t)(row0 + r) * ldc + col] = acc[i][j][r];
      } else {
        u16* C = (u16*)Cp;
#pragma unroll
        for (int r = 0; r < 4; r++)
          C[(size_t)(row0 + r) * ldc + col] = f2bf(acc[i][j][r]);
      }
    }
  (void)VT;
}

// ---------------- bf16 GEMM, 256x256 8-phase (m201 structure) ----------------
// 512 threads = 8 waves (2M x 4N); per-wave 128x64 output; BK=64, double-buffered
// 128KiB LDS. Per phase: stage 1 half-tile (global_load_lds, pre-swizzled global
// source -> linear LDS), ds_read_b128 frags through (row&7)<<4 XOR swizzle,
// setprio-wrapped 16 MFMA, raw s_barrier. Counted vmcnt(2) once per K-tile.
// MODE 0: bf16 C (ldc). MODE 2: qkv split — cols<4096 bf16 C; cols>=4096 (V)
// transposed to VT[(col-4096)*4096 + row].
template <int MODE>
__global__ __launch_bounds__(512, 2) void k_gemm256(
    const u16* __restrict__ A, const u16* __restrict__ Bm, void* __restrict__ Cp,
    u16* __restrict__ VT, int M, int N, int K, int ldc) {
  __shared__ __align__(16) char smem[131072];  // buf b: A @ b*65536, B @ +32768
  (void)M; (void)N;
  const int tid = threadIdx.x;
  const int lane = tid & 63;
  const int w = tid >> 6;
  const int l15 = lane & 15;
  const int quad = lane >> 4;
  const int wr = w >> 2;   // 0..1 -> A half
  const int wc = w & 3;    // 0..3 -> 64-col slice
  const int bm = blockIdx.y * 256;
  const int bn = blockIdx.x * 256;

  // ---- staging geometry ----
  // LDS tile (32KB) = 256 rows x 128B. slot s: row=s>>7, colbyte=s&127.
  // swizzle (involution): logical = s ^ ((row&7)<<4). global_load_lds writes
  // linearly, so the global SOURCE is pre-swizzled (rule #21).
  const int srow = w * 8 + (lane >> 3);                   // + h*128 + l*64
  const int scol = ((lane & 7) ^ ((lane >> 3) & 7)) * 8;  // swizzled source col
  const int sloff = w * 1024 + lane * 16;                 // LDS bytes in 8KB chunk
  const u16* const pa = A + (size_t)(bm + srow) * K + scol;
  const u16* const pb = Bm + (size_t)(bn + srow) * K + scol;
  const size_t rs64 = (size_t)64 * K;

  // ---- fragment-read geometry (same swizzle on the read side) ----
  const int fxor = (l15 & 7) << 4;
  const int c0 = (quad * 16) ^ fxor;        // ks=0 column bytes
  const int c1 = (64 + quad * 16) ^ fxor;   // ks=1
  const int aRow = (wr * 128 + l15) * 128;
  const int bRow = 32768 + (wc * 64 + l15) * 128;

  f32x4 acc[8][4] = {};
  const int NT = K >> 6;

  auto stage = [&](int ph, int buf, int kt) {
    const int isB = ph >> 1;
    const int h = ph & 1;
    const u16* g = (isB ? pb : pa) + (size_t)(h * 128) * K + kt * 64;
    char* l0 = smem + buf * 65536 + isB * 32768 + h * 16384 + sloff;
    async_ld16(g, l0);
    async_ld16(g + rs64, l0 + 8192);
  };

  // prologue: tile 0 into buf0 (8 loads/thread in flight)
#pragma unroll
  for (int ph = 0; ph < 4; ph++) stage(ph, 0, 0);

  for (int t = 0; t < NT; t++) {
    const char* base = smem + (t & 1) * 65536;
    bf16x8 bfr[2][4];
#pragma unroll
    for (int q = 0; q < 4; q++) {
      const bool pf = (t + 1 < NT);
      if (pf) stage(q, (t & 1) ^ 1, t + 1);  // prefetch half q of next tile
      if (q == 0) {
        // tile-t residency: all 8 loads of tile t landed; the 2 loads just
        // issued for tile t+1 stay in flight across the barrier (counted wait).
        if (pf) { asm volatile("s_waitcnt vmcnt(2)" ::: "memory"); }
        else    { asm volatile("s_waitcnt vmcnt(0)" ::: "memory"); }
        __builtin_amdgcn_s_barrier();
        asm volatile("" ::: "memory");
        // B fragments for the whole tile (reused by all 4 quadrants)
#pragma unroll
        for (int ni = 0; ni < 4; ni++) {
          bfr[0][ni] = *(const bf16x8*)(base + bRow + ni * 2048 + c0);
          bfr[1][ni] = *(const bf16x8*)(base + bRow + ni * 2048 + c1);
        }
      }
      // A fragments for this quadrant (mi = 2q, 2q+1)
      bf16x8 af[2][2];
#pragma unroll
      for (int dm = 0; dm < 2; dm++) {
        af[dm][0] = *(const bf16x8*)(base + aRow + (2 * q + dm) * 2048 + c0);
        af[dm][1] = *(const bf16x8*)(base + aRow + (2 * q + dm) * 2048 + c1);
      }
      __builtin_amdgcn_s_setprio(1);
#pragma unroll
      for (int dm = 0; dm < 2; dm++)
#pragma unroll
        for (int ni = 0; ni < 4; ni++) {
          acc[2 * q + dm][ni] = __builtin_amdgcn_mfma_f32_16x16x32_bf16(
              af[dm][0], bfr[0][ni], acc[2 * q + dm][ni], 0, 0, 0);
          acc[2 * q + dm][ni] = __builtin_amdgcn_mfma_f32_16x16x32_bf16(
              af[dm][1], bfr[1][ni], acc[2 * q + dm][ni], 0, 0, 0);
        }
      __builtin_amdgcn_s_setprio(0);
      asm volatile("" ::: "memory");
      __builtin_amdgcn_s_barrier();
      asm volatile("" ::: "memory");
    }
  }

  // C/D layout: col = lane&15, row = quad*4 + reg  [m89/m91 verified]
  if (MODE == 2 && bn >= 4096) {
#pragma unroll
    for (int mi = 0; mi < 8; mi++)
#pragma unroll
      for (int ni = 0; ni < 4; ni++) {
        const int row0 = bm + wr * 128 + mi * 16 + quad * 4;
        const int cv = bn + wc * 64 + ni * 16 + l15 - 4096;
        s16x4 o;
#pragma unroll
        for (int r = 0; r < 4; r++) o[r] = (short)f2bf(acc[mi][ni][r]);
        *(s16x4*)(VT + (size_t)cv * 4096 + row0) = o;
      }
    return;
  }
  u16* C = (u16*)Cp;
#pragma unroll
  for (int mi = 0; mi < 8; mi++)
#pragma unroll
    for (int ni = 0; ni < 4; ni++) {
      const int row0 = bm + wr * 128 + mi * 16 + quad * 4;
      const int col = bn + wc * 64 + ni * 16 + l15;
#pragma unroll
      for (int r = 0; r < 4; r++)
        C[(size_t)(row0 + r) * ldc + col] = f2bf(acc[mi][ni][r]);
    }
}

// ---------------- flash attention ----------------
// grid (S/128, H, B); block 256 = 4 waves; wave handles 32 q-rows.
__global__ __launch_bounds__(256) void k_flash(
    const u16* __restrict__ Qm, const u16* __restrict__ Km,
    const u16* __restrict__ VTm, u16* __restrict__ Om) {
  __shared__ __align__(16) u16 sK[32 * 136];   // [k_local][hd], stride 136
  __shared__ __align__(16) u16 sVT[128 * 40];  // [hd][k_local], stride 40
  __shared__ __align__(16) u16 sP[4][32 * 40]; // per-wave P, [q_local][k_local]

  const int tid = threadIdx.x;
  const int lane = tid & 63;
  const int wave = tid >> 6;
  const int l15 = lane & 15;
  const int quad = lane >> 4;

  const int b = blockIdx.z;
  const int h = blockIdx.y;
  const int q0 = blockIdx.x * 128;
  const int LDQ = 6144;
  const size_t rowbase = (size_t)b * 2048;

  bf16x8 aq[2][4];
#pragma unroll
  for (int mi = 0; mi < 2; mi++) {
    const u16* qp = Qm + (rowbase + q0 + wave * 32 + mi * 16 + l15) * LDQ + h * 128;
#pragma unroll
    for (int c = 0; c < 4; c++)
      aq[mi][c] = *(const bf16x8*)(qp + c * 32 + quad * 8);
  }

  f32x4 o[2][8] = {};
  float l[2][4] = {};

  const int kr0 = tid >> 4;
  const int kc = (tid & 15) * 8;
  const int vhd = tid >> 2;
  const int vko = (tid & 3) * 8;

  const u16* Kbase = Km + rowbase * LDQ + h * 128;
  const u16* Vbase = VTm + (size_t)(h * 128) * 4096 + rowbase;

  const float rs = 0.08838834764831845f;  // 1/sqrt(128)

  for (int k0 = 0; k0 < S_; k0 += 32) {
    __syncthreads();
    {
      const s16x8 kv0 = *(const s16x8*)(Kbase + (size_t)(k0 + kr0) * LDQ + kc);
      const s16x8 kv1 = *(const s16x8*)(Kbase + (size_t)(k0 + kr0 + 16) * LDQ + kc);
      const s16x8 vv0 = *(const s16x8*)(Vbase + (size_t)vhd * 4096 + k0 + vko);
      const s16x8 vv1 = *(const s16x8*)(Vbase + (size_t)(vhd + 64) * 4096 + k0 + vko);
      *(s16x8*)(&sK[kr0 * 136 + kc]) = kv0;
      *(s16x8*)(&sK[(kr0 + 16) * 136 + kc]) = kv1;
      *(s16x8*)(&sVT[vhd * 40 + vko]) = vv0;
      *(s16x8*)(&sVT[(vhd + 64) * 40 + vko]) = vv1;
    }
    __syncthreads();

    bf16x8 bk[2][4];
#pragma unroll
    for (int nt = 0; nt < 2; nt++)
#pragma unroll
      for (int c = 0; c < 4; c++)
        bk[nt][c] = *(const bf16x8*)(&sK[(nt * 16 + l15) * 136 + c * 32 + quad * 8]);

#pragma unroll
    for (int mi = 0; mi < 2; mi++) {
      f32x4 s[2] = {};
#pragma unroll
      for (int nt = 0; nt < 2; nt++)
#pragma unroll
        for (int c = 0; c < 4; c++)
          s[nt] = __builtin_amdgcn_mfma_f32_16x16x32_bf16(aq[mi][c], bk[nt][c],
                                                          s[nt], 0, 0, 0);
#pragma unroll
      for (int nt = 0; nt < 2; nt++)
#pragma unroll
        for (int r = 0; r < 4; r++) {
          float pv = __expf(s[nt][r] * rs);
          l[mi][r] += pv;
          sP[wave][(mi * 16 + quad * 4 + r) * 40 + nt * 16 + l15] = f2bf(pv);
        }
    }

    bf16x8 ap[2];
#pragma unroll
    for (int mi = 0; mi < 2; mi++)
      ap[mi] = *(const bf16x8*)(&sP[wave][(mi * 16 + l15) * 40 + quad * 8]);
#pragma unroll
    for (int ht = 0; ht < 8; ht++) {
      bf16x8 bv = *(const bf16x8*)(&sVT[(ht * 16 + l15) * 40 + quad * 8]);
#pragma unroll
      for (int mi = 0; mi < 2; mi++)
        o[mi][ht] = __builtin_amdgcn_mfma_f32_16x16x32_bf16(ap[mi], bv,
                                                            o[mi][ht], 0, 0, 0);
    }
  }

#pragma unroll
  for (int mi = 0; mi < 2; mi++)
#pragma unroll
    for (int r = 0; r < 4; r++) {
      float s = l[mi][r];
      s += __shfl_xor(s, 1);
      s += __shfl_xor(s, 2);
      s += __shfl_xor(s, 4);
      s += __shfl_xor(s, 8);
      l[mi][r] = 1.0f / s;
    }
#pragma unroll
  for (int mi = 0; mi < 2; mi++)
#pragma unroll
    for (int r = 0; r < 4; r++) {
      const size_t ro =
          (rowbase + q0 + wave * 32 + mi * 16 + quad * 4 + r) * (size_t)D_ +
          (size_t)h * HD_;
      const float inv = l[mi][r];
#pragma unroll
      for (int ht = 0; ht < 8; ht++)
        Om[ro + ht * 16 + l15] = f2bf(o[mi][ht][r] * inv);
    }
}

// ---------------- launcher ----------------
extern "C" void kernel_launch(void* const* d_in, const int* in_sizes, int n_in,
                              void* d_out, int out_size, void* d_ws, size_t ws_size,
                              hipStream_t stream) {
  (void)in_sizes; (void)n_in; (void)out_size;

  const float* x = (const float*)d_in[0];
  const float* y = (const float*)d_in[1];
  const float* attn_norm_w = (const float*)d_in[2];
  const float* wq[2] = {(const float*)d_in[3], (const float*)d_in[7]};
  const float* wk[2] = {(const float*)d_in[4], (const float*)d_in[8]};
  const float* wv[2] = {(const float*)d_in[5], (const float*)d_in[9]};
  const float* wo[2] = {(const float*)d_in[6], (const float*)d_in[10]};
  const float* w1[2] = {(const float*)d_in[11], (const float*)d_in[15]};
  const float* w2[2] = {(const float*)d_in[12], (const float*)d_in[16]};
  const float* w3[2] = {(const float*)d_in[13], (const float*)d_in[17]};
  const float* fnw[2] = {(const float*)d_in[14], (const float*)d_in[18]};

  char* ws = (char*)d_ws;
  const size_t A0 = 0;            // 16.8M: xn, later ao (flash out)
  const size_t A1 = 16777216;     // 16.8M: yn, later hb_x
  const size_t W_ = 33554432;     // 46.1M: weight slot (bf16)
  const size_t Q1 = 79691776;     // 50.3M: qkvA; later gcat (spans Q1+Q2) / ff
  const size_t Q2 = 130023424;    // 50.3M: qkvB
  const size_t V1 = 180355072;    // 16.8M: VT_A; later hb_y
  const size_t V2 = 197132288;    // 16.8M: VT_B
  const size_t GB = 213909504;    // 46.1M: gbuf
  const size_t NEED = 260046848;
  if (ws_size < NEED) {
    fprintf(stderr, "kernel_launch: ws too small: %zu < %zu\n", ws_size, NEED);
    return;
  }
  u16* xn = (u16*)(ws + A0);
  u16* yn = (u16*)(ws + A1);
  u16* wslot = (u16*)(ws + W_);
  u16* qkvA = (u16*)(ws + Q1);
  u16* qkvB = (u16*)(ws + Q2);
  u16* vtA = (u16*)(ws + V1);
  u16* vtB = (u16*)(ws + V2);
  u16* ao = (u16*)(ws + A0);      // xn dead after QKV GEMMs
  u16* hbx = (u16*)(ws + A1);     // yn dead after QKV GEMMs
  u16* hby = (u16*)(ws + V1);     // VT_A dead after flash y
  u16* gcat = (u16*)(ws + Q1);    // qkvA/B dead after flash y (spans Q1..Q2)
  u16* gbuf = (u16*)(ws + GB);
  float* ff = (float*)(ws + Q1);  // gcat dead after silu

  const size_t WOFF = (size_t)2048 * 2048;

  k_rmsnorm_bf16<<<4096, 256, 0, stream>>>(x, attn_norm_w, xn);
  k_rmsnorm_bf16<<<4096, 256, 0, stream>>>(y, attn_norm_w, yn);

  const dim3 gqkv(24, 16);   // 6144/256 x 4096/256
  const dim3 gproj(16, 32);  // 128^2 kernel
  const dim3 gw13(44, 16);   // 11264/256 x 4096/256

  // QKV merged: qkvA = xn @ [wq_x; wk_y; wv_y]^T  (V part -> vtA transposed)
  k_cvt_bf16<<<2048, 256, 0, stream>>>(wq[0], wslot, 524288);
  k_cvt_bf16<<<2048, 256, 0, stream>>>(wk[1], wslot + WOFF, 524288);
  k_cvt_bf16<<<2048, 256, 0, stream>>>(wv[1], wslot + 2 * WOFF, 524288);
  k_gemm256<2><<<gqkv, 512, 0, stream>>>(xn, wslot, qkvA, vtA, 4096, 6144, 2048, 6144);
  // qkvB = yn @ [wq_y; wk_x; wv_x]^T  (V part -> vtB transposed)
  k_cvt_bf16<<<2048, 256, 0, stream>>>(wq[1], wslot, 524288);
  k_cvt_bf16<<<2048, 256, 0, stream>>>(wk[0], wslot + WOFF, 524288);
  k_cvt_bf16<<<2048, 256, 0, stream>>>(wv[0], wslot + 2 * WOFF, 524288);
  k_gemm256<2><<<gqkv, 512, 0, stream>>>(yn, wslot, qkvB, vtB, 4096, 6144, 2048, 6144);

  // side x attention: Q=qkvA[:,0:2048], K=qkvB[:,2048:4096], V=vtB
  k_flash<<<dim3(16, 16, 2), 256, 0, stream>>>(qkvA, qkvB + 2048, vtB, ao);
  k_cvt_bf16<<<2048, 256, 0, stream>>>(wo[0], wslot, 524288);
  k_gemm_bt<0><<<gproj, 256, 0, stream>>>(ao, wslot, hbx, nullptr, 4096, 2048, 2048, 2048);

  // side y attention: Q=qkvB[:,0:2048], K=qkvA[:,2048:4096], V=vtA
  k_flash<<<dim3(16, 16, 2), 256, 0, stream>>>(qkvB, qkvA + 2048, vtA, ao);
  k_cvt_bf16<<<2048, 256, 0, stream>>>(wo[1], wslot, 524288);
  k_gemm_bt<0><<<gproj, 256, 0, stream>>>(ao, wslot, hby, nullptr, 4096, 2048, 2048, 2048);

  const float* resid[2] = {x, y};
  float* outp[2] = {(float*)d_out, (float*)d_out + (size_t)8388608};
  u16* hb[2] = {hbx, hby};
  const size_t W13OFF = (size_t)FF_ * 2048;

  for (int s = 0; s < 2; s++) {
    k_cvt_bf16<<<5632, 256, 0, stream>>>(w1[s], wslot, 1441792);
    k_cvt_bf16<<<5632, 256, 0, stream>>>(w3[s], wslot + W13OFF, 1441792);
    k_gemm256<0><<<gw13, 512, 0, stream>>>(hb[s], wslot, gcat, nullptr, 4096, 11264, 2048, 11264);
    k_silu_mul<<<11264, 256, 0, stream>>>(gcat, gbuf);
    k_cvt_bf16<<<5632, 256, 0, stream>>>(w2[s], wslot, 1441792);
    k_gemm_bt<1><<<gproj, 256, 0, stream>>>(gbuf, wslot, ff, nullptr, 4096, 2048, 5632, 2048);
    k_add_rmsnorm<<<4096, 256, 0, stream>>>(ff, resid[s], fnw[s], outp[s]);
  }
}

// Round 3
// 1600.498 us; speedup vs baseline: 1.1073x; 1.0529x over previous
//
#include <hip/hip_runtime.h>
#include <cstdio>
#include <cstdint>
#include <cstddef>

// Problem constants
#define B_ 2
#define S_ 2048
#define D_ 2048
#define H_ 16
#define HD_ 128
#define FF_ 5632

typedef unsigned short u16;
typedef float f32x4 __attribute__((ext_vector_type(4)));
typedef __bf16 bf16x8 __attribute__((ext_vector_type(8)));
typedef short s16x8 __attribute__((ext_vector_type(8)));
typedef short s16x4 __attribute__((ext_vector_type(4)));

__device__ __forceinline__ u16 f2bf(float f) {
  unsigned u = __builtin_bit_cast(unsigned, f);
  u += 0x7fffu + ((u >> 16) & 1u);   // RNE
  return (u16)(u >> 16);
}
__device__ __forceinline__ float bf2f(u16 h) {
  unsigned u = ((unsigned)h) << 16;
  return __builtin_bit_cast(float, u);
}

// async global->LDS, 16B per lane. LDS dest must be wave-uniform base + lane*16.
__device__ __forceinline__ void async_ld16(const void* g, void* l) {
  __builtin_amdgcn_global_load_lds(
      (__attribute__((address_space(1))) void*)(unsigned long long)g,
      (__attribute__((address_space(3))) void*)(unsigned)(unsigned long long)l,
      16, 0, 0);
}

// ---------------- f32 -> bf16 convert (8 elems/thread) ----------------
__global__ __launch_bounds__(256) void k_cvt_bf16(
    const float* __restrict__ in, u16* __restrict__ out, int n8) {
  const int i = blockIdx.x * 256 + threadIdx.x;
  if (i >= n8) return;
  const float4* p = (const float4*)in + (size_t)i * 2;
  const float4 a = p[0], b = p[1];
  s16x8 o;
  o[0] = (short)f2bf(a.x); o[1] = (short)f2bf(a.y);
  o[2] = (short)f2bf(a.z); o[3] = (short)f2bf(a.w);
  o[4] = (short)f2bf(b.x); o[5] = (short)f2bf(b.y);
  o[6] = (short)f2bf(b.z); o[7] = (short)f2bf(b.w);
  *(s16x8*)(out + (size_t)i * 8) = o;
}

// ---------------- RMSNorm (f32 in, bf16 out), one block per row of 2048 ----------------
__global__ __launch_bounds__(256) void k_rmsnorm_bf16(
    const float* __restrict__ x, const float* __restrict__ w, u16* __restrict__ out) {
  const int row = blockIdx.x;
  const int t = threadIdx.x;
  const float* xr = x + (size_t)row * D_;
  const float4 a = ((const float4*)xr)[t];
  const float4 b = ((const float4*)xr)[t + 256];
  float ss = a.x * a.x + a.y * a.y + a.z * a.z + a.w * a.w +
             b.x * b.x + b.y * b.y + b.z * b.z + b.w * b.w;
#pragma unroll
  for (int off = 1; off < 64; off <<= 1) ss += __shfl_xor(ss, off);
  __shared__ float red[4];
  if ((t & 63) == 0) red[t >> 6] = ss;
  __syncthreads();
  const float scale =
      rsqrtf((red[0] + red[1] + red[2] + red[3]) * (1.0f / (float)D_) + 1e-5f);
  const float4 wa = ((const float4*)w)[t];
  const float4 wb = ((const float4*)w)[t + 256];
  u16* orow = out + (size_t)row * D_;
  s16x4 o0, o1;
  o0[0] = (short)f2bf(a.x * scale * wa.x);
  o0[1] = (short)f2bf(a.y * scale * wa.y);
  o0[2] = (short)f2bf(a.z * scale * wa.z);
  o0[3] = (short)f2bf(a.w * scale * wa.w);
  o1[0] = (short)f2bf(b.x * scale * wb.x);
  o1[1] = (short)f2bf(b.y * scale * wb.y);
  o1[2] = (short)f2bf(b.z * scale * wb.z);
  o1[3] = (short)f2bf(b.w * scale * wb.w);
  *(s16x4*)(orow + t * 4) = o0;
  *(s16x4*)(orow + (t + 256) * 4) = o1;
}

// ---------------- ff + residual -> RMSNorm -> f32 out ----------------
__global__ __launch_bounds__(256) void k_add_rmsnorm(
    const float* __restrict__ ff, const float* __restrict__ res,
    const float* __restrict__ w, float* __restrict__ out) {
  const int row = blockIdx.x;
  const int t = threadIdx.x;
  const float4 fa = ((const float4*)(ff + (size_t)row * D_))[t];
  const float4 fb = ((const float4*)(ff + (size_t)row * D_))[t + 256];
  const float4 ra = ((const float4*)(res + (size_t)row * D_))[t];
  const float4 rb = ((const float4*)(res + (size_t)row * D_))[t + 256];
  float4 ha, hb2;
  ha.x = fa.x + ra.x; ha.y = fa.y + ra.y; ha.z = fa.z + ra.z; ha.w = fa.w + ra.w;
  hb2.x = fb.x + rb.x; hb2.y = fb.y + rb.y; hb2.z = fb.z + rb.z; hb2.w = fb.w + rb.w;
  float ss = ha.x * ha.x + ha.y * ha.y + ha.z * ha.z + ha.w * ha.w +
             hb2.x * hb2.x + hb2.y * hb2.y + hb2.z * hb2.z + hb2.w * hb2.w;
#pragma unroll
  for (int off = 1; off < 64; off <<= 1) ss += __shfl_xor(ss, off);
  __shared__ float red[4];
  if ((t & 63) == 0) red[t >> 6] = ss;
  __syncthreads();
  const float scale =
      rsqrtf((red[0] + red[1] + red[2] + red[3]) * (1.0f / (float)D_) + 1e-5f);
  const float4 wa = ((const float4*)w)[t];
  const float4 wb = ((const float4*)w)[t + 256];
  float4 o0, o1;
  o0.x = ha.x * scale * wa.x; o0.y = ha.y * scale * wa.y;
  o0.z = ha.z * scale * wa.z; o0.w = ha.w * scale * wa.w;
  o1.x = hb2.x * scale * wb.x; o1.y = hb2.y * scale * wb.y;
  o1.z = hb2.z * scale * wb.z; o1.w = hb2.w * scale * wb.w;
  float* orow = out + (size_t)row * D_;
  ((float4*)orow)[t] = o0;
  ((float4*)orow)[t + 256] = o1;
}

// ---------------- silu(g)*u from merged gcat [4096, 11264] -> gbuf [4096, 5632] ----------------
__global__ __launch_bounds__(256) void k_silu_mul(
    const u16* __restrict__ gcat, u16* __restrict__ out) {
  const int idx = blockIdx.x * 256 + threadIdx.x;  // 4096*704 total
  const int row = idx / 704;
  const int c = (idx - row * 704) * 8;
  const s16x8 gv = *(const s16x8*)(gcat + (size_t)row * 11264 + c);
  const s16x8 uv = *(const s16x8*)(gcat + (size_t)row * 11264 + 5632 + c);
  s16x8 ov;
#pragma unroll
  for (int j = 0; j < 8; j++) {
    float gf = bf2f((u16)gv[j]);
    float uf = bf2f((u16)uv[j]);
    float s = gf / (1.0f + __expf(-gf));
    ov[j] = (short)f2bf(s * uf);
  }
  *(s16x8*)(out + (size_t)row * 5632 + c) = ov;
}

// ---------------- bf16 GEMM, 256x128 tile, BK=64, ring-3 LDS pipeline ----------------
// 512 threads = 8 waves (4M x 2N); per-wave 64x64 output (4mi x 4ni frags).
// LDS: 3 ring buffers x 48KB (A 256x64 = 32KB, B 128x64 = 16KB). Tile t+2 is
// staged (6 global_load_lds units of 8KB) during tile t's compute -> every
// load has >= 2 full tiles' compute of lead. One counted vmcnt(6) + one
// barrier per K-tile; never drain to 0 in the main loop.
// Ring safety: tile t+2 writes buf[(t+2)%3] == buf[(t-1)%3]; all its readers
// are past the tile-t entry barrier before any stage issues (their ds_reads
// are consumed by MFMAs that precede the barrier in program order).
// XOR swizzle (row&7)<<4 on byte offset: linear LDS dest + pre-swizzled
// global source + swizzled ds_read (rule #21) -> 0 bank conflicts.
// MODE 0: bf16 C. MODE 1: f32 C. MODE 2: qkv split (cols>=4096 -> VT^T).
template <int MODE>
__global__ __launch_bounds__(512, 2) void k_gemmR(
    const u16* __restrict__ A, const u16* __restrict__ Bm, void* __restrict__ Cp,
    u16* __restrict__ VT, int K, int ldc) {
  __shared__ __align__(16) char smem[147456];  // 3 x 49152
  const int tid = threadIdx.x;
  const int lane = tid & 63;
  const int w = tid >> 6;
  const int l15 = lane & 15;
  const int quad = lane >> 4;
  const int wr = w >> 1;   // 0..3 -> 64-row slice
  const int wc = w & 1;    // 0..1 -> 64-col slice

  // XCD-aware bijective swizzle (all grids are multiples of 8 blocks)
  const int gx = gridDim.x;
  const int nwg = gx * gridDim.y;
  const int flat = blockIdx.y * gx + blockIdx.x;
  const int swz = (flat & 7) * (nwg >> 3) + (flat >> 3);
  const int bm = (swz / gx) * 256;
  const int bn = (swz % gx) * 128;

  // ---- staging geometry: unit = 8KB = 64 rows x 128B, 1 load/thread ----
  const int srow = tid >> 3;                                  // row within unit
  const int scol = ((tid & 7) ^ ((tid >> 3) & 7)) * 8;        // pre-swizzled col (elems)
  const int sloff = tid * 16;                                 // linear LDS dest
  const u16* const pa = A + (size_t)(bm + srow) * K + scol;
  const u16* const pb = Bm + (size_t)(bn + srow) * K + scol;

  // unit u: 0..3 = A rows u*64.., 4..5 = B rows (u-4)*64..
  auto stage = [&](int u, int kt, int ring) {
    char* base = smem + ring;
    if (u < 4)
      async_ld16(pa + (size_t)(u * 64) * K + kt * 64, base + u * 8192 + sloff);
    else
      async_ld16(pb + (size_t)((u - 4) * 64) * K + kt * 64,
                 base + 32768 + (u - 4) * 8192 + sloff);
  };

  // ---- fragment-read geometry (same swizzle on read side) ----
  const int fxor = (l15 & 7) << 4;
  const int c0 = (quad * 16) ^ fxor;        // ks=0 byte col
  const int c1 = (64 + quad * 16) ^ fxor;   // ks=1
  const int aRow = (wr * 64 + l15) * 128;
  const int bRow = 32768 + (wc * 64 + l15) * 128;

  f32x4 acc[4][4] = {};
  const int NT = K >> 6;

  // prologue: tiles 0 and 1 fully staged (12 loads/thread in flight)
#pragma unroll
  for (int u = 0; u < 6; u++) stage(u, 0, 0);
#pragma unroll
  for (int u = 0; u < 6; u++) stage(u, 1, 49152);

  int rcur = 0, rnext = 49152, rstage = 98304;

  for (int t = 0; t < NT; t++) {
    // drain tile t's 6 loads; keep tile t+1's 6 in flight (counted wait)
    if (t + 1 < NT) { asm volatile("s_waitcnt vmcnt(6)" ::: "memory"); }
    else            { asm volatile("s_waitcnt vmcnt(0)" ::: "memory"); }
    __builtin_amdgcn_s_barrier();
    asm volatile("" ::: "memory");

    const char* cb = smem + rcur;
    const bool pf = (t + 2 < NT);

    // phase 0: stage half of tile t+2, B frags (whole tile) + A frags mi 0,1
    if (pf) { stage(0, t + 2, rstage); stage(1, t + 2, rstage); stage(2, t + 2, rstage); }
    bf16x8 bfr[2][4];
#pragma unroll
    for (int ni = 0; ni < 4; ni++) {
      bfr[0][ni] = *(const bf16x8*)(cb + bRow + ni * 2048 + c0);
      bfr[1][ni] = *(const bf16x8*)(cb + bRow + ni * 2048 + c1);
    }
    {
      bf16x8 af[2][2];
#pragma unroll
      for (int dm = 0; dm < 2; dm++) {
        af[dm][0] = *(const bf16x8*)(cb + aRow + dm * 2048 + c0);
        af[dm][1] = *(const bf16x8*)(cb + aRow + dm * 2048 + c1);
      }
      __builtin_amdgcn_s_setprio(1);
#pragma unroll
      for (int dm = 0; dm < 2; dm++)
#pragma unroll
        for (int ni = 0; ni < 4; ni++) {
          acc[dm][ni] = __builtin_amdgcn_mfma_f32_16x16x32_bf16(
              af[dm][0], bfr[0][ni], acc[dm][ni], 0, 0, 0);
          acc[dm][ni] = __builtin_amdgcn_mfma_f32_16x16x32_bf16(
              af[dm][1], bfr[1][ni], acc[dm][ni], 0, 0, 0);
        }
      __builtin_amdgcn_s_setprio(0);
    }

    // phase 1: stage other half of tile t+2, A frags mi 2,3
    if (pf) { stage(3, t + 2, rstage); stage(4, t + 2, rstage); stage(5, t + 2, rstage); }
    {
      bf16x8 af[2][2];
#pragma unroll
      for (int dm = 0; dm < 2; dm++) {
        af[dm][0] = *(const bf16x8*)(cb + aRow + (2 + dm) * 2048 + c0);
        af[dm][1] = *(const bf16x8*)(cb + aRow + (2 + dm) * 2048 + c1);
      }
      __builtin_amdgcn_s_setprio(1);
#pragma unroll
      for (int dm = 0; dm < 2; dm++)
#pragma unroll
        for (int ni = 0; ni < 4; ni++) {
          acc[2 + dm][ni] = __builtin_amdgcn_mfma_f32_16x16x32_bf16(
              af[dm][0], bfr[0][ni], acc[2 + dm][ni], 0, 0, 0);
          acc[2 + dm][ni] = __builtin_amdgcn_mfma_f32_16x16x32_bf16(
              af[dm][1], bfr[1][ni], acc[2 + dm][ni], 0, 0, 0);
        }
      __builtin_amdgcn_s_setprio(0);
    }
    asm volatile("" ::: "memory");

    const int tmp = rcur; rcur = rnext; rnext = rstage; rstage = tmp;
  }

  // C/D layout: col = lane&15, row = quad*4 + reg  [m89/m91 verified]
  if (MODE == 2 && bn >= 4096) {
#pragma unroll
    for (int mi = 0; mi < 4; mi++)
#pragma unroll
      for (int ni = 0; ni < 4; ni++) {
        const int row0 = bm + wr * 64 + mi * 16 + quad * 4;
        const int cv = bn + wc * 64 + ni * 16 + l15 - 4096;
        s16x4 o;
#pragma unroll
        for (int r = 0; r < 4; r++) o[r] = (short)f2bf(acc[mi][ni][r]);
        *(s16x4*)(VT + (size_t)cv * 4096 + row0) = o;
      }
    return;
  }
#pragma unroll
  for (int mi = 0; mi < 4; mi++)
#pragma unroll
    for (int ni = 0; ni < 4; ni++) {
      const int row0 = bm + wr * 64 + mi * 16 + quad * 4;
      const int col = bn + wc * 64 + ni * 16 + l15;
      if (MODE == 1) {
        float* C = (float*)Cp;
#pragma unroll
        for (int r = 0; r < 4; r++)
          C[(size_t)(row0 + r) * ldc + col] = acc[mi][ni][r];
      } else {
        u16* C = (u16*)Cp;
#pragma unroll
        for (int r = 0; r < 4; r++)
          C[(size_t)(row0 + r) * ldc + col] = f2bf(acc[mi][ni][r]);
      }
    }
}

// ---------------- flash attention ----------------
// grid (S/128, H, B); block 256 = 4 waves; wave handles 32 q-rows.
__global__ __launch_bounds__(256) void k_flash(
    const u16* __restrict__ Qm, const u16* __restrict__ Km,
    const u16* __restrict__ VTm, u16* __restrict__ Om) {
  __shared__ __align__(16) u16 sK[32 * 136];   // [k_local][hd], stride 136
  __shared__ __align__(16) u16 sVT[128 * 40];  // [hd][k_local], stride 40
  __shared__ __align__(16) u16 sP[4][32 * 40]; // per-wave P, [q_local][k_local]

  const int tid = threadIdx.x;
  const int lane = tid & 63;
  const int wave = tid >> 6;
  const int l15 = lane & 15;
  const int quad = lane >> 4;

  const int b = blockIdx.z;
  const int h = blockIdx.y;
  const int q0 = blockIdx.x * 128;
  const int LDQ = 6144;
  const size_t rowbase = (size_t)b * 2048;

  bf16x8 aq[2][4];
#pragma unroll
  for (int mi = 0; mi < 2; mi++) {
    const u16* qp = Qm + (rowbase + q0 + wave * 32 + mi * 16 + l15) * LDQ + h * 128;
#pragma unroll
    for (int c = 0; c < 4; c++)
      aq[mi][c] = *(const bf16x8*)(qp + c * 32 + quad * 8);
  }

  f32x4 o[2][8] = {};
  float l[2][4] = {};

  const int kr0 = tid >> 4;
  const int kc = (tid & 15) * 8;
  const int vhd = tid >> 2;
  const int vko = (tid & 3) * 8;

  const u16* Kbase = Km + rowbase * LDQ + h * 128;
  const u16* Vbase = VTm + (size_t)(h * 128) * 4096 + rowbase;

  const float rs = 0.08838834764831845f;  // 1/sqrt(128)

  for (int k0 = 0; k0 < S_; k0 += 32) {
    __syncthreads();
    {
      const s16x8 kv0 = *(const s16x8*)(Kbase + (size_t)(k0 + kr0) * LDQ + kc);
      const s16x8 kv1 = *(const s16x8*)(Kbase + (size_t)(k0 + kr0 + 16) * LDQ + kc);
      const s16x8 vv0 = *(const s16x8*)(Vbase + (size_t)vhd * 4096 + k0 + vko);
      const s16x8 vv1 = *(const s16x8*)(Vbase + (size_t)(vhd + 64) * 4096 + k0 + vko);
      *(s16x8*)(&sK[kr0 * 136 + kc]) = kv0;
      *(s16x8*)(&sK[(kr0 + 16) * 136 + kc]) = kv1;
      *(s16x8*)(&sVT[vhd * 40 + vko]) = vv0;
      *(s16x8*)(&sVT[(vhd + 64) * 40 + vko]) = vv1;
    }
    __syncthreads();

    bf16x8 bk[2][4];
#pragma unroll
    for (int nt = 0; nt < 2; nt++)
#pragma unroll
      for (int c = 0; c < 4; c++)
        bk[nt][c] = *(const bf16x8*)(&sK[(nt * 16 + l15) * 136 + c * 32 + quad * 8]);

#pragma unroll
    for (int mi = 0; mi < 2; mi++) {
      f32x4 s[2] = {};
#pragma unroll
      for (int nt = 0; nt < 2; nt++)
#pragma unroll
        for (int c = 0; c < 4; c++)
          s[nt] = __builtin_amdgcn_mfma_f32_16x16x32_bf16(aq[mi][c], bk[nt][c],
                                                          s[nt], 0, 0, 0);
#pragma unroll
      for (int nt = 0; nt < 2; nt++)
#pragma unroll
        for (int r = 0; r < 4; r++) {
          float pv = __expf(s[nt][r] * rs);
          l[mi][r] += pv;
          sP[wave][(mi * 16 + quad * 4 + r) * 40 + nt * 16 + l15] = f2bf(pv);
        }
    }

    bf16x8 ap[2];
#pragma unroll
    for (int mi = 0; mi < 2; mi++)
      ap[mi] = *(const bf16x8*)(&sP[wave][(mi * 16 + l15) * 40 + quad * 8]);
#pragma unroll
    for (int ht = 0; ht < 8; ht++) {
      bf16x8 bv = *(const bf16x8*)(&sVT[(ht * 16 + l15) * 40 + quad * 8]);
#pragma unroll
      for (int mi = 0; mi < 2; mi++)
        o[mi][ht] = __builtin_amdgcn_mfma_f32_16x16x32_bf16(ap[mi], bv,
                                                            o[mi][ht], 0, 0, 0);
    }
  }

#pragma unroll
  for (int mi = 0; mi < 2; mi++)
#pragma unroll
    for (int r = 0; r < 4; r++) {
      float s = l[mi][r];
      s += __shfl_xor(s, 1);
      s += __shfl_xor(s, 2);
      s += __shfl_xor(s, 4);
      s += __shfl_xor(s, 8);
      l[mi][r] = 1.0f / s;
    }
#pragma unroll
  for (int mi = 0; mi < 2; mi++)
#pragma unroll
    for (int r = 0; r < 4; r++) {
      const size_t ro =
          (rowbase + q0 + wave * 32 + mi * 16 + quad * 4 + r) * (size_t)D_ +
          (size_t)h * HD_;
      const float inv = l[mi][r];
#pragma unroll
      for (int ht = 0; ht < 8; ht++)
        Om[ro + ht * 16 + l15] = f2bf(o[mi][ht][r] * inv);
    }
}

// ---------------- launcher ----------------
extern "C" void kernel_launch(void* const* d_in, const int* in_sizes, int n_in,
                              void* d_out, int out_size, void* d_ws, size_t ws_size,
                              hipStream_t stream) {
  (void)in_sizes; (void)n_in; (void)out_size;

  const float* x = (const float*)d_in[0];
  const float* y = (const float*)d_in[1];
  const float* attn_norm_w = (const float*)d_in[2];
  const float* wq[2] = {(const float*)d_in[3], (const float*)d_in[7]};
  const float* wk[2] = {(const float*)d_in[4], (const float*)d_in[8]};
  const float* wv[2] = {(const float*)d_in[5], (const float*)d_in[9]};
  const float* wo[2] = {(const float*)d_in[6], (const float*)d_in[10]};
  const float* w1[2] = {(const float*)d_in[11], (const float*)d_in[15]};
  const float* w2[2] = {(const float*)d_in[12], (const float*)d_in[16]};
  const float* w3[2] = {(const float*)d_in[13], (const float*)d_in[17]};
  const float* fnw[2] = {(const float*)d_in[14], (const float*)d_in[18]};

  char* ws = (char*)d_ws;
  const size_t A0 = 0;            // 16.8M: xn, later ao (flash out)
  const size_t A1 = 16777216;     // 16.8M: yn, later hb_x
  const size_t W_ = 33554432;     // 46.1M: weight slot (bf16)
  const size_t Q1 = 79691776;     // 50.3M: qkvA; later gcat (spans Q1+Q2) / ff
  const size_t Q2 = 130023424;    // 50.3M: qkvB
  const size_t V1 = 180355072;    // 16.8M: VT_A; later hb_y
  const size_t V2 = 197132288;    // 16.8M: VT_B
  const size_t GB = 213909504;    // 46.1M: gbuf
  const size_t NEED = 260046848;
  if (ws_size < NEED) {
    fprintf(stderr, "kernel_launch: ws too small: %zu < %zu\n", ws_size, NEED);
    return;
  }
  u16* xn = (u16*)(ws + A0);
  u16* yn = (u16*)(ws + A1);
  u16* wslot = (u16*)(ws + W_);
  u16* qkvA = (u16*)(ws + Q1);
  u16* qkvB = (u16*)(ws + Q2);
  u16* vtA = (u16*)(ws + V1);
  u16* vtB = (u16*)(ws + V2);
  u16* ao = (u16*)(ws + A0);      // xn dead after QKV GEMMs
  u16* hbx = (u16*)(ws + A1);     // yn dead after QKV GEMMs
  u16* hby = (u16*)(ws + V1);     // VT_A dead after flash y
  u16* gcat = (u16*)(ws + Q1);    // qkvA/B dead after flash y (spans Q1..Q2)
  u16* gbuf = (u16*)(ws + GB);
  float* ff = (float*)(ws + Q1);  // gcat dead after silu

  const size_t WOFF = (size_t)2048 * 2048;

  k_rmsnorm_bf16<<<4096, 256, 0, stream>>>(x, attn_norm_w, xn);
  k_rmsnorm_bf16<<<4096, 256, 0, stream>>>(y, attn_norm_w, yn);

  const dim3 gqkv(48, 16);   // 6144/128 x 4096/256
  const dim3 gproj(16, 16);  // 2048/128 x 4096/256
  const dim3 gw13(88, 16);   // 11264/128 x 4096/256

  // QKV merged: qkvA = xn @ [wq_x; wk_y; wv_y]^T  (V part -> vtA transposed)
  k_cvt_bf16<<<2048, 256, 0, stream>>>(wq[0], wslot, 524288);
  k_cvt_bf16<<<2048, 256, 0, stream>>>(wk[1], wslot + WOFF, 524288);
  k_cvt_bf16<<<2048, 256, 0, stream>>>(wv[1], wslot + 2 * WOFF, 524288);
  k_gemmR<2><<<gqkv, 512, 0, stream>>>(xn, wslot, qkvA, vtA, 2048, 6144);
  // qkvB = yn @ [wq_y; wk_x; wv_x]^T  (V part -> vtB transposed)
  k_cvt_bf16<<<2048, 256, 0, stream>>>(wq[1], wslot, 524288);
  k_cvt_bf16<<<2048, 256, 0, stream>>>(wk[0], wslot + WOFF, 524288);
  k_cvt_bf16<<<2048, 256, 0, stream>>>(wv[0], wslot + 2 * WOFF, 524288);
  k_gemmR<2><<<gqkv, 512, 0, stream>>>(yn, wslot, qkvB, vtB, 2048, 6144);

  // side x attention: Q=qkvA[:,0:2048], K=qkvB[:,2048:4096], V=vtB
  k_flash<<<dim3(16, 16, 2), 256, 0, stream>>>(qkvA, qkvB + 2048, vtB, ao);
  k_cvt_bf16<<<2048, 256, 0, stream>>>(wo[0], wslot, 524288);
  k_gemmR<0><<<gproj, 512, 0, stream>>>(ao, wslot, hbx, nullptr, 2048, 2048);

  // side y attention: Q=qkvB[:,0:2048], K=qkvA[:,2048:4096], V=vtA
  k_flash<<<dim3(16, 16, 2), 256, 0, stream>>>(qkvB, qkvA + 2048, vtA, ao);
  k_cvt_bf16<<<2048, 256, 0, stream>>>(wo[1], wslot, 524288);
  k_gemmR<0><<<gproj, 512, 0, stream>>>(ao, wslot, hby, nullptr, 2048, 2048);

  const float* resid[2] = {x, y};
  float* outp[2] = {(float*)d_out, (float*)d_out + (size_t)8388608};
  u16* hb[2] = {hbx, hby};
  const size_t W13OFF = (size_t)FF_ * 2048;

  for (int s = 0; s < 2; s++) {
    k_cvt_bf16<<<5632, 256, 0, stream>>>(w1[s], wslot, 1441792);
    k_cvt_bf16<<<5632, 256, 0, stream>>>(w3[s], wslot + W13OFF, 1441792);
    k_gemmR<0><<<gw13, 512, 0, stream>>>(hb[s], wslot, gcat, nullptr, 2048, 11264);
    k_silu_mul<<<11264, 256, 0, stream>>>(gcat, gbuf);
    k_cvt_bf16<<<5632, 256, 0, stream>>>(w2[s], wslot, 1441792);
    k_gemmR<1><<<gproj, 512, 0, stream>>>(gbuf, wslot, ff, nullptr, 5632, 2048);
    k_add_rmsnorm<<<4096, 256, 0, stream>>>(ff, resid[s], fnw[s], outp[s]);
  }
}